// Round 12
// baseline (88.793 us; speedup 1.0000x reference)
//
#include <hip/hip_runtime.h>

constexpr int B_   = 4;
constexpr int NL   = 8192;
constexpr int NH   = 2048;
constexpr int CH   = 256;
constexpr int CL   = 128;
constexpr int CIN  = 384;
constexpr int COUT = 256;

typedef _Float16 f16;
typedef _Float16 f16x8 __attribute__((ext_vector_type(8)));
typedef float    f32x4 __attribute__((ext_vector_type(4)));

// Branchless top-3 insert (strict < == earliest-index-wins on ties).
#define BINS(d, h, B0, B1, B2, I0, I1, I2) do {                              \
    bool m2_ = (d) < (B2); B2 = m2_ ? (d) : B2; I2 = m2_ ? (h) : I2;         \
    bool m1_ = (B2) < (B1);                                                  \
    { float t_ = B1; int ti_ = I1;                                           \
      B1 = m1_ ? B2 : B1; I1 = m1_ ? I2 : I1;                                \
      B2 = m1_ ? t_ : B2; I2 = m1_ ? ti_ : I2; }                             \
    bool m0_ = (B1) < (B0);                                                  \
    { float t_ = B0; int ti_ = I0;                                           \
      B0 = m0_ ? B1 : B0; I0 = m0_ ? I1 : I0;                                \
      B1 = m0_ ? t_ : B1; I1 = m0_ ? ti_ : I1; }                             \
} while (0)

// ---------------------------------------------------------------------------
// K1: role-fused.
//   [0,1024):    3-NN quarter-range blocks, 128 points each (2 per lane ->
//                2 independent insert chains per broadcast pts[h] read).
//                Block = (tile<<2)|qt, tile = 128-point tile (256 total).
//                Wave w scans [qt*512 + w*128, +128). 12-way slice-order
//                merge -> per-quarter top-3 (d2, idx) raw to cdG/ciG.
//   [1024,1536): fhT transpose (B,CH,NH) f32 -> (B,NH,CH) f16.
//   [1536,2560): flT transpose (B,CL,NL) f32 -> (B,NL,CL) f16.
//   [2560,2944): W f32 -> f16.
// ---------------------------------------------------------------------------
__global__ __launch_bounds__(256) void knn_prep_kernel(
    const float* __restrict__ xyz_low, const float* __restrict__ xyz_high,
    const float* __restrict__ feat_high, const float* __restrict__ feat_low,
    const float* __restrict__ Wm,
    f16* __restrict__ fhT, f16* __restrict__ flT, f16* __restrict__ Wh,
    float* __restrict__ cdG, int* __restrict__ ciG)
{
    __shared__ __align__(16) char smraw[18304];
    const int bid = blockIdx.x, tid = threadIdx.x;

    if (bid < 1024) {
        float4*         pts = (float4*)smraw;                  // [0, 8192)
        float*          md  = (float*)(smraw + 8192);          // 128*13 f32
        unsigned short* mi  = (unsigned short*)(smraw + 14848);// 128*13 u16
        const int tile = bid >> 2, qt = bid & 3;
        const int b = tile >> 6, l0 = (tile & 63) * 128;
        const int w = tid >> 6, p = tid & 63;
        const int hbase = qt * 512;

        const float* xh = xyz_high + ((size_t)b * NH + hbase) * 3;
        for (int h = tid; h < 512; h += 256) {
            float x = xh[h * 3], yy = xh[h * 3 + 1], z = xh[h * 3 + 2];
            pts[h] = make_float4(x, yy, z, x * x + yy * yy + z * z);
        }
        __syncthreads();

        const float* xlA = xyz_low + ((size_t)b * NL + l0 + p) * 3;
        const float* xlB = xyz_low + ((size_t)b * NL + l0 + 64 + p) * 3;
        const float lxA = xlA[0], lyA = xlA[1], lzA = xlA[2];
        const float lxB = xlB[0], lyB = xlB[1], lzB = xlB[2];
        const float slA = lxA * lxA + lyA * lyA + lzA * lzA;
        const float slB = lxB * lxB + lyB * lyB + lzB * lzB;

        float a0 = 1e30f, a1 = 1e30f, a2 = 1e30f;
        float c0 = 1e30f, c1 = 1e30f, c2 = 1e30f;
        int ia0 = 0, ia1 = 0, ia2 = 0, ic0 = 0, ic1 = 0, ic2 = 0;
        const int h0 = w * 128;
        #pragma unroll 4
        for (int h = h0; h < h0 + 128; ++h) {
            float4 pt = pts[h];
            float dA = fmaf(-2.0f, fmaf(lxA, pt.x, fmaf(lyA, pt.y, lzA * pt.z)),
                            slA + pt.w);
            float dB = fmaf(-2.0f, fmaf(lxB, pt.x, fmaf(lyB, pt.y, lzB * pt.z)),
                            slB + pt.w);
            BINS(dA, h, a0, a1, a2, ia0, ia1, ia2);
            BINS(dB, h, c0, c1, c2, ic0, ic1, ic2);
        }
        const int cbA = p * 13 + w * 3;
        const int cbB = (p + 64) * 13 + w * 3;
        md[cbA] = a0;     mi[cbA] = (unsigned short)(hbase + ia0);
        md[cbA + 1] = a1; mi[cbA + 1] = (unsigned short)(hbase + ia1);
        md[cbA + 2] = a2; mi[cbA + 2] = (unsigned short)(hbase + ia2);
        md[cbB] = c0;     mi[cbB] = (unsigned short)(hbase + ic0);
        md[cbB + 1] = c1; mi[cbB + 1] = (unsigned short)(hbase + ic1);
        md[cbB + 2] = c2; mi[cbB + 2] = (unsigned short)(hbase + ic2);
        __syncthreads();

        if (tid < 128) {  // merge 12 in slice order (h ascending, tie-stable)
            float e0 = 1e30f, e1 = 1e30f, e2 = 1e30f;
            int j0 = 0, j1 = 0, j2 = 0;
            #pragma unroll
            for (int q = 0; q < 12; ++q) {
                float d = md[tid * 13 + q];
                int  ii = mi[tid * 13 + q];
                BINS(d, ii, e0, e1, e2, j0, j1, j2);
            }
            const size_t dst = (size_t)bid * 384 + tid;
            cdG[dst]       = e0; ciG[dst]       = j0;
            cdG[dst + 128] = e1; ciG[dst + 128] = j1;
            cdG[dst + 256] = e2; ciG[dst + 256] = j2;
        }
    } else if (bid < 1536) {
        float (*tt)[33] = (float(*)[33])smraw;
        const int tx = tid & 31, ty = tid >> 5;
        #pragma unroll
        for (int k = 0; k < 4; ++k) {
            const int u  = (bid - 1024) * 4 + k;       // 2048 tiles
            const int ub = u >> 9, ut = u & 511;
            const int h0 = (ut & 63) * 32, c0 = (ut >> 6) * 32;
            #pragma unroll
            for (int pp = 0; pp < 4; ++pp)
                tt[ty + pp * 8][tx] =
                    feat_high[((size_t)ub * CH + c0 + ty + pp * 8) * NH + h0 + tx];
            __syncthreads();
            #pragma unroll
            for (int pp = 0; pp < 4; ++pp)
                fhT[((size_t)ub * NH + h0 + ty + pp * 8) * CH + c0 + tx] =
                    (f16)tt[tx][ty + pp * 8];
            __syncthreads();
        }
    } else if (bid < 2560) {
        float (*tt)[33] = (float(*)[33])smraw;
        const int tx = tid & 31, ty = tid >> 5;
        #pragma unroll
        for (int k = 0; k < 4; ++k) {
            const int u  = (bid - 1536) * 4 + k;       // 4096 tiles
            const int ub = u >> 10, ut = u & 1023;
            const int l0 = (ut & 255) * 32, c0 = (ut >> 8) * 32;
            #pragma unroll
            for (int pp = 0; pp < 4; ++pp)
                tt[ty + pp * 8][tx] =
                    feat_low[((size_t)ub * CL + c0 + ty + pp * 8) * NL + l0 + tx];
            __syncthreads();
            #pragma unroll
            for (int pp = 0; pp < 4; ++pp)
                flT[((size_t)ub * NL + l0 + ty + pp * 8) * CL + c0 + tx] =
                    (f16)tt[tx][ty + pp * 8];
            __syncthreads();
        }
    } else {
        const int i = (bid - 2560) * 256 + tid;        // 384 blocks
        Wh[i] = (f16)Wm[i];
    }
}

// ---------------------------------------------------------------------------
// K2: interpolation. 2048 blocks x 256 thr (16 points each). Merge the 4
// quarter triples (h order, strict < -> exact tie semantics) -> weights;
// gather fhT rows; write DENSE ficat (B,NL,256) fp16 (d_out-as-scratch).
// ---------------------------------------------------------------------------
__global__ __launch_bounds__(256) void interp_kernel(
    const f16* __restrict__ fhT,
    const float* __restrict__ cdG, const int* __restrict__ ciG,
    f16* __restrict__ ficat)
{
    __shared__ int   idxL[3 * 16];
    __shared__ float wL[3 * 16];

    const int bid = blockIdx.x, tid = threadIdx.x;
    const int b = bid >> 9, l0b = (bid & 511) * 16;

    if (tid < 16) {   // cross-quarter merge + weights for 16 points
        float e0 = 1e30f, e1 = 1e30f, e2 = 1e30f;
        int j0 = 0, j1 = 0, j2 = 0;
        const int tile = b * 64 + (l0b >> 7);          // 128-pt tile
        const int poff = (l0b & 127) + tid;
        #pragma unroll
        for (int qt = 0; qt < 4; ++qt) {
            const size_t src = (size_t)(tile * 4 + qt) * 384 + poff;
            #pragma unroll
            for (int q = 0; q < 3; ++q) {
                float d = cdG[src + q * 128];
                int  ii = ciG[src + q * 128];
                BINS(d, ii, e0, e1, e2, j0, j1, j2);
            }
        }
        float d0 = sqrtf(fmaxf(e0, 0.0f));
        float d1 = sqrtf(fmaxf(e1, 0.0f));
        float d2f = sqrtf(fmaxf(e2, 0.0f));
        float iw0 = 1.0f / fmaxf(d0, 1e-8f);
        float iw1 = 1.0f / fmaxf(d1, 1e-8f);
        float iw2 = 1.0f / fmaxf(d2f, 1e-8f);
        float sum = iw0 + iw1 + iw2;
        idxL[tid] = j0; idxL[16 + tid] = j1; idxL[32 + tid] = j2;
        wL[tid] = iw0 / sum; wL[16 + tid] = iw1 / sum; wL[32 + tid] = iw2 / sum;
    }
    __syncthreads();

    const int p = tid & 15, q = tid >> 4;              // q = 0..15, 16 ch each
    const int j0 = idxL[p], j1 = idxL[16 + p], j2 = idxL[32 + p];
    const float u0 = wL[p], u1 = wL[16 + p], u2 = wL[32 + p];
    const f16* r0 = fhT + ((size_t)b * NH + j0) * CH + q * 16;
    const f16* r1 = fhT + ((size_t)b * NH + j1) * CH + q * 16;
    const f16* r2 = fhT + ((size_t)b * NH + j2) * CH + q * 16;
    f16* dst = ficat + (((size_t)b * NL + l0b + p) << 8) + q * 16;
    #pragma unroll
    for (int j = 0; j < 2; ++j) {
        f16x8 v0 = *(const f16x8*)(r0 + j * 8);
        f16x8 v1 = *(const f16x8*)(r1 + j * 8);
        f16x8 v2 = *(const f16x8*)(r2 + j * 8);
        f16x8 o;
        #pragma unroll
        for (int e = 0; e < 8; ++e)
            o[e] = (f16)(u0 * (float)v0[e] + u1 * (float)v1[e]
                         + u2 * (float)v2[e]);
        *(f16x8*)(dst + j * 8) = o;
    }
}

// ---------------------------------------------------------------------------
// K3: pure streaming GEMM. 512 blocks x 512 thr (wave w owns 32 o x 64 l).
// As[64][392] staged fully coalesced (ficat + flT, both dense f16);
// barrier-free 12-kt K-loop, W A-frags from L2-hot global; bias into acc;
// per-block BN partials; yh stores 128B/row.
// ---------------------------------------------------------------------------
__global__ __launch_bounds__(512) void gemm_kernel(
    const f16* __restrict__ flT, const f16* __restrict__ ficat,
    const f16* __restrict__ Wh, const float* __restrict__ bias,
    f16* __restrict__ yh, float* __restrict__ ps, float* __restrict__ psq)
{
    __shared__ __align__(16) char smraw[50176];
    f16* As = (f16*)smraw;

    const int bid = blockIdx.x, tid = threadIdx.x;
    const int b = bid >> 7, l0 = (bid & 127) * 64;
    const int lane = tid & 63, w = tid >> 6;

    {   // stage: row = tid>>3 (64 rows), q = tid&7 (32 interp + 16 low ch)
        const int row = tid >> 3, q = tid & 7;
        const f16* src = ficat + (((size_t)b * NL + l0 + row) << 8) + q * 32;
        #pragma unroll
        for (int j = 0; j < 4; ++j)
            *(f16x8*)&As[row * 392 + q * 32 + j * 8] =
                *(const f16x8*)(src + j * 8);
        const f16* fl2 = flT + ((size_t)b * NL + l0 + row) * CL + q * 16;
        *(f16x8*)&As[row * 392 + 256 + q * 16]     = *(const f16x8*)(fl2);
        *(f16x8*)&As[row * 392 + 256 + q * 16 + 8] = *(const f16x8*)(fl2 + 8);
    }
    __syncthreads();

    f32x4 acc[2][4] = {};
    const int kb = (lane >> 4) * 8;
    const int r  = lane & 15;
    #pragma unroll
    for (int kt = 0; kt < 12; ++kt) {
        const int k0 = kt * 32;
        f16x8 a[2], bb[4];
        #pragma unroll
        for (int mi = 0; mi < 2; ++mi)
            a[mi] = *(const f16x8*)&Wh[(size_t)(w * 32 + mi * 16 + r) * CIN
                                       + k0 + kb];
        #pragma unroll
        for (int ni = 0; ni < 4; ++ni)
            bb[ni] = *(const f16x8*)&As[(ni * 16 + r) * 392 + k0 + kb];
        #pragma unroll
        for (int mi = 0; mi < 2; ++mi)
            #pragma unroll
            for (int ni = 0; ni < 4; ++ni)
                acc[mi][ni] = __builtin_amdgcn_mfma_f32_16x16x32_f16(
                    a[mi], bb[ni], acc[mi][ni], 0, 0, 0);
    }

    // bias into acc + per-block BN partials (no LDS touched)
    const int r4 = (lane >> 4) * 4, cl = lane & 15;
    #pragma unroll
    for (int mi = 0; mi < 2; ++mi) {
        #pragma unroll
        for (int j = 0; j < 4; ++j) {
            const int o = w * 32 + mi * 16 + r4 + j;
            const float bi = bias[o];
            float s = 0.0f, sq = 0.0f;
            #pragma unroll
            for (int ni = 0; ni < 4; ++ni) {
                acc[mi][ni][j] += bi;
                float v = acc[mi][ni][j];
                s += v; sq += v * v;
            }
            #pragma unroll
            for (int m = 1; m < 16; m <<= 1) {
                s  += __shfl_xor(s, m);
                sq += __shfl_xor(sq, m);
            }
            if (cl == 0) {
                ps [o * 512 + bid] = s;
                psq[o * 512 + bid] = sq;
            }
        }
    }
    __syncthreads();   // all As reads done -> safe to alias with Ys

    f16* Ys = (f16*)smraw;             // [256][72] f16 = 36864 B
    #pragma unroll
    for (int mi = 0; mi < 2; ++mi)
        #pragma unroll
        for (int j = 0; j < 4; ++j) {
            const int o = w * 32 + mi * 16 + r4 + j;
            #pragma unroll
            for (int ni = 0; ni < 4; ++ni)
                Ys[o * 72 + cl + ni * 16] = (f16)acc[mi][ni][j];
        }
    __syncthreads();
    {   // store: 2 threads per o-row -> 128B contiguous per row
        const int o = tid >> 1, half = tid & 1;
        f16* dst = yh + ((size_t)b * COUT + o) * NL + l0 + half * 32;
        #pragma unroll
        for (int j = 0; j < 4; ++j)
            *(f16x8*)(dst + j * 8) = *(const f16x8*)&Ys[o * 72 + half * 32 + j * 8];
    }
}

// ---------------------------------------------------------------------------
// K4: fused BN stats + apply + ReLU. Grid (COUT, B_): each block reduces its
// channel's 512 partials (deterministic, redundant across b-blocks) then
// applies to its (b,o) row (overwrites the ficat scratch in d_out).
// ---------------------------------------------------------------------------
__global__ __launch_bounds__(256) void stats_apply_kernel(
    const float* __restrict__ ps, const float* __restrict__ psq,
    const f16* __restrict__ yh,
    const float* __restrict__ gamma, const float* __restrict__ beta,
    float* __restrict__ y)
{
    const int o = blockIdx.x, b = blockIdx.y, tid = threadIdx.x;
    const int w = tid >> 6, lane = tid & 63;

    float s = ps[o * 512 + tid] + ps[o * 512 + 256 + tid];
    float q = psq[o * 512 + tid] + psq[o * 512 + 256 + tid];
    #pragma unroll
    for (int m = 32; m > 0; m >>= 1) {
        s += __shfl_down(s, m);
        q += __shfl_down(q, m);
    }
    __shared__ float red[8];
    if (lane == 0) { red[w] = s; red[4 + w] = q; }
    __syncthreads();
    s = red[0] + red[1] + red[2] + red[3];
    q = red[4] + red[5] + red[6] + red[7];
    const float n  = (float)(B_ * NL);
    const float mu = s / n;
    const float rs = rsqrtf(q / n - mu * mu + 1e-5f);
    const float g  = gamma[o], be = beta[o];

    const f16* src = yh + ((size_t)b * COUT + o) * NL;
    float*     dst = y  + ((size_t)b * COUT + o) * NL;
    #pragma unroll
    for (int it = 0; it < 4; ++it) {
        const int base = it * 2048 + tid * 8;
        f16x8 v = *(const f16x8*)(src + base);
        float4 o1, o2;
        o1.x = fmaxf(fmaf(g, ((float)v[0] - mu) * rs, be), 0.0f);
        o1.y = fmaxf(fmaf(g, ((float)v[1] - mu) * rs, be), 0.0f);
        o1.z = fmaxf(fmaf(g, ((float)v[2] - mu) * rs, be), 0.0f);
        o1.w = fmaxf(fmaf(g, ((float)v[3] - mu) * rs, be), 0.0f);
        o2.x = fmaxf(fmaf(g, ((float)v[4] - mu) * rs, be), 0.0f);
        o2.y = fmaxf(fmaf(g, ((float)v[5] - mu) * rs, be), 0.0f);
        o2.z = fmaxf(fmaf(g, ((float)v[6] - mu) * rs, be), 0.0f);
        o2.w = fmaxf(fmaf(g, ((float)v[7] - mu) * rs, be), 0.0f);
        *(float4*)(dst + base)     = o1;
        *(float4*)(dst + base + 4) = o2;
    }
}

// ---------------------------------------------------------------------------
extern "C" void kernel_launch(void* const* d_in, const int* in_sizes, int n_in,
                              void* d_out, int out_size, void* d_ws, size_t ws_size,
                              hipStream_t stream)
{
    const float* xyz_low   = (const float*)d_in[0];
    const float* xyz_high  = (const float*)d_in[1];
    const float* feat_low  = (const float*)d_in[2];
    const float* feat_high = (const float*)d_in[3];
    const float* Wm        = (const float*)d_in[4];
    const float* bias      = (const float*)d_in[5];
    const float* gamma     = (const float*)d_in[6];
    const float* beta      = (const float*)d_in[7];
    float* y = (float*)d_out;

    float* ps   = (float*)d_ws;                        // 256*512 f32
    float* psq  = ps + (size_t)COUT * 512;             // 256*512 f32
    float* cdG  = psq + (size_t)COUT * 512;            // 1024*384 f32
    int*   ciG  = (int*)(cdG + (size_t)1024 * 384);    // 1024*384 i32
    f16*   Wh   = (f16*)(ciG + (size_t)1024 * 384);    // 256*384 f16
    f16*   fhT  = Wh + (size_t)COUT * CIN;             // 4*2048*256 f16 (4.2MB)
    f16*   flT  = fhT + (size_t)B_ * NH * CH;          // 4*8192*128 f16 (8.4MB)
    f16*   yh   = flT + (size_t)B_ * NL * CL;          // 4*256*8192 f16 (16.8MB)
    f16*   ficat = (f16*)d_out;                        // scratch: dead by K4

    knn_prep_kernel<<<2944, 256, 0, stream>>>(
        xyz_low, xyz_high, feat_high, feat_low, Wm, fhT, flT, Wh, cdG, ciG);
    interp_kernel<<<2048, 256, 0, stream>>>(fhT, cdG, ciG, ficat);
    gemm_kernel<<<512, 512, 0, stream>>>(
        flT, ficat, Wh, bias, yh, ps, psq);
    stats_apply_kernel<<<dim3(COUT, B_), 256, 0, stream>>>(
        ps, psq, yh, gamma, beta, y);
}

// Round 13
// 85.328 us; speedup vs baseline: 1.0406x; 1.0406x over previous
//
#include <hip/hip_runtime.h>

constexpr int B_   = 4;
constexpr int NL   = 8192;
constexpr int NH   = 2048;
constexpr int CH   = 256;
constexpr int CL   = 128;
constexpr int CIN  = 384;
constexpr int COUT = 256;

typedef _Float16 f16;
typedef _Float16 f16x8 __attribute__((ext_vector_type(8)));
typedef float    f32x4 __attribute__((ext_vector_type(4)));

// Fast branchless top-3 insert: 3 cmp + 5 cndmask (indices) + min/med3/med3
// (values) = 11 flat ops, dependency depth 2. Bit-equivalent to the
// sequential strict-< insert incl. earliest-index-wins on exact ties:
//   d<b0: (h,i0,i1) shift; b0<=d<b1: i1=h shift; b1<=d<b2: i2=h; d>=b2: noop.
#define INS3F(d, h, B0, B1, B2, I0, I1, I2) do {                             \
    bool c0_ = (d) < (B0), c1_ = (d) < (B1), c2_ = (d) < (B2);               \
    int ni1_ = c0_ ? (I0) : (c1_ ? (h) : (I1));                              \
    int ni2_ = c1_ ? (I1) : (c2_ ? (h) : (I2));                              \
    I0 = c0_ ? (h) : (I0); I1 = ni1_; I2 = ni2_;                             \
    float nb1_ = __builtin_amdgcn_fmed3f(B0, B1, (d));                       \
    float nb2_ = __builtin_amdgcn_fmed3f(B1, B2, (d));                       \
    B0 = fminf(B0, (d)); B1 = nb1_; B2 = nb2_;                               \
} while (0)

// ---------------------------------------------------------------------------
// K1: role-fused.
//   [0,2048):    3-NN eighth-range blocks: block=(tile<<3)|oct. 128 low pts
//                (2 per lane) vs h in [oct*256, oct*256+256). Wave w scans a
//                64-h slice; pts[h] wave-uniform -> LDS broadcast. 12-way
//                slice-order merge -> per-octant top-3 (d2,idx) to cdG/ciG.
//                ~14 KB LDS -> 8 blocks/CU = 32 waves/CU on the knn phase.
//   [2048,2560): fhT transpose (B,CH,NH) f32 -> (B,NH,CH) f16.
//   [2560,3584): flT transpose (B,CL,NL) f32 -> (B,NL,CL) f16.
//   [3584,3968): W f32 -> f16.
// ---------------------------------------------------------------------------
__global__ __launch_bounds__(256) void knn_prep_kernel(
    const float* __restrict__ xyz_low, const float* __restrict__ xyz_high,
    const float* __restrict__ feat_high, const float* __restrict__ feat_low,
    const float* __restrict__ Wm,
    f16* __restrict__ fhT, f16* __restrict__ flT, f16* __restrict__ Wh,
    float* __restrict__ cdG, int* __restrict__ ciG)
{
    __shared__ __align__(16) char smraw[14080];
    const int bid = blockIdx.x, tid = threadIdx.x;

    if (bid < 2048) {
        float4*         pts = (float4*)smraw;                  // [0, 4096)
        float*          md  = (float*)(smraw + 4096);          // 128*13 f32
        unsigned short* mi  = (unsigned short*)(smraw + 10752);// 128*13 u16
        const int tile = bid >> 3, oct = bid & 7;
        const int b = tile >> 6, l0 = (tile & 63) * 128;
        const int w = tid >> 6, p = tid & 63;
        const int hbase = oct * 256;

        const float* xh = xyz_high + ((size_t)b * NH + hbase) * 3;
        {
            const int h = tid;  // 256 pts, 256 threads
            float x = xh[h * 3], yy = xh[h * 3 + 1], z = xh[h * 3 + 2];
            pts[h] = make_float4(x, yy, z, x * x + yy * yy + z * z);
        }
        __syncthreads();

        const float* xlA = xyz_low + ((size_t)b * NL + l0 + p) * 3;
        const float* xlB = xyz_low + ((size_t)b * NL + l0 + 64 + p) * 3;
        const float lxA = xlA[0], lyA = xlA[1], lzA = xlA[2];
        const float lxB = xlB[0], lyB = xlB[1], lzB = xlB[2];
        const float slA = lxA * lxA + lyA * lyA + lzA * lzA;
        const float slB = lxB * lxB + lyB * lyB + lzB * lzB;

        float a0 = 1e30f, a1 = 1e30f, a2 = 1e30f;
        float c0 = 1e30f, c1 = 1e30f, c2 = 1e30f;
        int ia0 = 0, ia1 = 0, ia2 = 0, ic0 = 0, ic1 = 0, ic2 = 0;
        const int h0 = w * 64;
        #pragma unroll 4
        for (int h = h0; h < h0 + 64; ++h) {
            float4 pt = pts[h];
            float dA = fmaf(-2.0f, fmaf(lxA, pt.x, fmaf(lyA, pt.y, lzA * pt.z)),
                            slA + pt.w);
            float dB = fmaf(-2.0f, fmaf(lxB, pt.x, fmaf(lyB, pt.y, lzB * pt.z)),
                            slB + pt.w);
            INS3F(dA, h, a0, a1, a2, ia0, ia1, ia2);
            INS3F(dB, h, c0, c1, c2, ic0, ic1, ic2);
        }
        const int cbA = p * 13 + w * 3;
        const int cbB = (p + 64) * 13 + w * 3;
        md[cbA] = a0;     mi[cbA] = (unsigned short)(hbase + ia0);
        md[cbA + 1] = a1; mi[cbA + 1] = (unsigned short)(hbase + ia1);
        md[cbA + 2] = a2; mi[cbA + 2] = (unsigned short)(hbase + ia2);
        md[cbB] = c0;     mi[cbB] = (unsigned short)(hbase + ic0);
        md[cbB + 1] = c1; mi[cbB + 1] = (unsigned short)(hbase + ic1);
        md[cbB + 2] = c2; mi[cbB + 2] = (unsigned short)(hbase + ic2);
        __syncthreads();

        if (tid < 128) {  // merge 12 in slice order (h ascending, tie-stable)
            float e0 = 1e30f, e1 = 1e30f, e2 = 1e30f;
            int j0 = 0, j1 = 0, j2 = 0;
            #pragma unroll
            for (int q = 0; q < 12; ++q) {
                float d = md[tid * 13 + q];
                int  ii = mi[tid * 13 + q];
                INS3F(d, ii, e0, e1, e2, j0, j1, j2);
            }
            const size_t dst = (size_t)bid * 384 + tid;
            cdG[dst]       = e0; ciG[dst]       = j0;
            cdG[dst + 128] = e1; ciG[dst + 128] = j1;
            cdG[dst + 256] = e2; ciG[dst + 256] = j2;
        }
    } else if (bid < 2560) {
        float (*tt)[33] = (float(*)[33])smraw;
        const int tx = tid & 31, ty = tid >> 5;
        #pragma unroll
        for (int k = 0; k < 4; ++k) {
            const int u  = (bid - 2048) * 4 + k;       // 2048 tiles
            const int ub = u >> 9, ut = u & 511;
            const int h0 = (ut & 63) * 32, c0 = (ut >> 6) * 32;
            #pragma unroll
            for (int pp = 0; pp < 4; ++pp)
                tt[ty + pp * 8][tx] =
                    feat_high[((size_t)ub * CH + c0 + ty + pp * 8) * NH + h0 + tx];
            __syncthreads();
            #pragma unroll
            for (int pp = 0; pp < 4; ++pp)
                fhT[((size_t)ub * NH + h0 + ty + pp * 8) * CH + c0 + tx] =
                    (f16)tt[tx][ty + pp * 8];
            __syncthreads();
        }
    } else if (bid < 3584) {
        float (*tt)[33] = (float(*)[33])smraw;
        const int tx = tid & 31, ty = tid >> 5;
        #pragma unroll
        for (int k = 0; k < 4; ++k) {
            const int u  = (bid - 2560) * 4 + k;       // 4096 tiles
            const int ub = u >> 10, ut = u & 1023;
            const int l0 = (ut & 255) * 32, c0 = (ut >> 8) * 32;
            #pragma unroll
            for (int pp = 0; pp < 4; ++pp)
                tt[ty + pp * 8][tx] =
                    feat_low[((size_t)ub * CL + c0 + ty + pp * 8) * NL + l0 + tx];
            __syncthreads();
            #pragma unroll
            for (int pp = 0; pp < 4; ++pp)
                flT[((size_t)ub * NL + l0 + ty + pp * 8) * CL + c0 + tx] =
                    (f16)tt[tx][ty + pp * 8];
            __syncthreads();
        }
    } else {
        const int i = (bid - 3584) * 256 + tid;        // 384 blocks
        Wh[i] = (f16)Wm[i];
    }
}

// ---------------------------------------------------------------------------
// K2: interpolation. 2048 blocks x 256 thr (16 points each). Merge the 8
// octant triples (h order, strict < -> exact tie semantics) -> weights;
// gather fhT rows; write DENSE ficat (B,NL,256) fp16 (d_out-as-scratch).
// ---------------------------------------------------------------------------
__global__ __launch_bounds__(256) void interp_kernel(
    const f16* __restrict__ fhT,
    const float* __restrict__ cdG, const int* __restrict__ ciG,
    f16* __restrict__ ficat)
{
    __shared__ int   idxL[3 * 16];
    __shared__ float wL[3 * 16];

    const int bid = blockIdx.x, tid = threadIdx.x;
    const int b = bid >> 9, l0b = (bid & 511) * 16;

    if (tid < 16) {   // cross-octant merge + weights for 16 points
        float e0 = 1e30f, e1 = 1e30f, e2 = 1e30f;
        int j0 = 0, j1 = 0, j2 = 0;
        const int tile = b * 64 + (l0b >> 7);          // 128-pt tile
        const int poff = (l0b & 127) + tid;
        #pragma unroll
        for (int oct = 0; oct < 8; ++oct) {
            const size_t src = (size_t)(tile * 8 + oct) * 384 + poff;
            #pragma unroll
            for (int q = 0; q < 3; ++q) {
                float d = cdG[src + q * 128];
                int  ii = ciG[src + q * 128];
                INS3F(d, ii, e0, e1, e2, j0, j1, j2);
            }
        }
        float d0 = sqrtf(fmaxf(e0, 0.0f));
        float d1 = sqrtf(fmaxf(e1, 0.0f));
        float d2f = sqrtf(fmaxf(e2, 0.0f));
        float iw0 = 1.0f / fmaxf(d0, 1e-8f);
        float iw1 = 1.0f / fmaxf(d1, 1e-8f);
        float iw2 = 1.0f / fmaxf(d2f, 1e-8f);
        float sum = iw0 + iw1 + iw2;
        idxL[tid] = j0; idxL[16 + tid] = j1; idxL[32 + tid] = j2;
        wL[tid] = iw0 / sum; wL[16 + tid] = iw1 / sum; wL[32 + tid] = iw2 / sum;
    }
    __syncthreads();

    const int p = tid & 15, q = tid >> 4;              // q = 0..15, 16 ch each
    const int j0 = idxL[p], j1 = idxL[16 + p], j2 = idxL[32 + p];
    const float u0 = wL[p], u1 = wL[16 + p], u2 = wL[32 + p];
    const f16* r0 = fhT + ((size_t)b * NH + j0) * CH + q * 16;
    const f16* r1 = fhT + ((size_t)b * NH + j1) * CH + q * 16;
    const f16* r2 = fhT + ((size_t)b * NH + j2) * CH + q * 16;
    f16* dst = ficat + (((size_t)b * NL + l0b + p) << 8) + q * 16;
    #pragma unroll
    for (int j = 0; j < 2; ++j) {
        f16x8 v0 = *(const f16x8*)(r0 + j * 8);
        f16x8 v1 = *(const f16x8*)(r1 + j * 8);
        f16x8 v2 = *(const f16x8*)(r2 + j * 8);
        f16x8 o;
        #pragma unroll
        for (int e = 0; e < 8; ++e)
            o[e] = (f16)(u0 * (float)v0[e] + u1 * (float)v1[e]
                         + u2 * (float)v2[e]);
        *(f16x8*)(dst + j * 8) = o;
    }
}

// ---------------------------------------------------------------------------
// K3: pure streaming GEMM. 512 blocks x 512 thr (wave w owns 32 o x 64 l).
// As[64][392] staged fully coalesced (ficat + flT, both dense f16);
// barrier-free 12-kt K-loop, W A-frags from L2-hot global; bias into acc;
// per-block BN partials; yh stores 128B/row.
// ---------------------------------------------------------------------------
__global__ __launch_bounds__(512) void gemm_kernel(
    const f16* __restrict__ flT, const f16* __restrict__ ficat,
    const f16* __restrict__ Wh, const float* __restrict__ bias,
    f16* __restrict__ yh, float* __restrict__ ps, float* __restrict__ psq)
{
    __shared__ __align__(16) char smraw[50176];
    f16* As = (f16*)smraw;

    const int bid = blockIdx.x, tid = threadIdx.x;
    const int b = bid >> 7, l0 = (bid & 127) * 64;
    const int lane = tid & 63, w = tid >> 6;

    {   // stage: row = tid>>3 (64 rows), q = tid&7 (32 interp + 16 low ch)
        const int row = tid >> 3, q = tid & 7;
        const f16* src = ficat + (((size_t)b * NL + l0 + row) << 8) + q * 32;
        #pragma unroll
        for (int j = 0; j < 4; ++j)
            *(f16x8*)&As[row * 392 + q * 32 + j * 8] =
                *(const f16x8*)(src + j * 8);
        const f16* fl2 = flT + ((size_t)b * NL + l0 + row) * CL + q * 16;
        *(f16x8*)&As[row * 392 + 256 + q * 16]     = *(const f16x8*)(fl2);
        *(f16x8*)&As[row * 392 + 256 + q * 16 + 8] = *(const f16x8*)(fl2 + 8);
    }
    __syncthreads();

    f32x4 acc[2][4] = {};
    const int kb = (lane >> 4) * 8;
    const int r  = lane & 15;
    #pragma unroll
    for (int kt = 0; kt < 12; ++kt) {
        const int k0 = kt * 32;
        f16x8 a[2], bb[4];
        #pragma unroll
        for (int mi = 0; mi < 2; ++mi)
            a[mi] = *(const f16x8*)&Wh[(size_t)(w * 32 + mi * 16 + r) * CIN
                                       + k0 + kb];
        #pragma unroll
        for (int ni = 0; ni < 4; ++ni)
            bb[ni] = *(const f16x8*)&As[(ni * 16 + r) * 392 + k0 + kb];
        #pragma unroll
        for (int mi = 0; mi < 2; ++mi)
            #pragma unroll
            for (int ni = 0; ni < 4; ++ni)
                acc[mi][ni] = __builtin_amdgcn_mfma_f32_16x16x32_f16(
                    a[mi], bb[ni], acc[mi][ni], 0, 0, 0);
    }

    // bias into acc + per-block BN partials (no LDS touched)
    const int r4 = (lane >> 4) * 4, cl = lane & 15;
    #pragma unroll
    for (int mi = 0; mi < 2; ++mi) {
        #pragma unroll
        for (int j = 0; j < 4; ++j) {
            const int o = w * 32 + mi * 16 + r4 + j;
            const float bi = bias[o];
            float s = 0.0f, sq = 0.0f;
            #pragma unroll
            for (int ni = 0; ni < 4; ++ni) {
                acc[mi][ni][j] += bi;
                float v = acc[mi][ni][j];
                s += v; sq += v * v;
            }
            #pragma unroll
            for (int m = 1; m < 16; m <<= 1) {
                s  += __shfl_xor(s, m);
                sq += __shfl_xor(sq, m);
            }
            if (cl == 0) {
                ps [o * 512 + bid] = s;
                psq[o * 512 + bid] = sq;
            }
        }
    }
    __syncthreads();   // all As reads done -> safe to alias with Ys

    f16* Ys = (f16*)smraw;             // [256][72] f16 = 36864 B
    #pragma unroll
    for (int mi = 0; mi < 2; ++mi)
        #pragma unroll
        for (int j = 0; j < 4; ++j) {
            const int o = w * 32 + mi * 16 + r4 + j;
            #pragma unroll
            for (int ni = 0; ni < 4; ++ni)
                Ys[o * 72 + cl + ni * 16] = (f16)acc[mi][ni][j];
        }
    __syncthreads();
    {   // store: 2 threads per o-row -> 128B contiguous per row
        const int o = tid >> 1, half = tid & 1;
        f16* dst = yh + ((size_t)b * COUT + o) * NL + l0 + half * 32;
        #pragma unroll
        for (int j = 0; j < 4; ++j)
            *(f16x8*)(dst + j * 8) = *(const f16x8*)&Ys[o * 72 + half * 32 + j * 8];
    }
}

// ---------------------------------------------------------------------------
// K4: fused BN stats + apply + ReLU. Grid (COUT, B_): each block reduces its
// channel's 512 partials (deterministic, redundant across b-blocks) then
// applies to its (b,o) row (overwrites the ficat scratch in d_out).
// ---------------------------------------------------------------------------
__global__ __launch_bounds__(256) void stats_apply_kernel(
    const float* __restrict__ ps, const float* __restrict__ psq,
    const f16* __restrict__ yh,
    const float* __restrict__ gamma, const float* __restrict__ beta,
    float* __restrict__ y)
{
    const int o = blockIdx.x, b = blockIdx.y, tid = threadIdx.x;
    const int w = tid >> 6, lane = tid & 63;

    float s = ps[o * 512 + tid] + ps[o * 512 + 256 + tid];
    float q = psq[o * 512 + tid] + psq[o * 512 + 256 + tid];
    #pragma unroll
    for (int m = 32; m > 0; m >>= 1) {
        s += __shfl_down(s, m);
        q += __shfl_down(q, m);
    }
    __shared__ float red[8];
    if (lane == 0) { red[w] = s; red[4 + w] = q; }
    __syncthreads();
    s = red[0] + red[1] + red[2] + red[3];
    q = red[4] + red[5] + red[6] + red[7];
    const float n  = (float)(B_ * NL);
    const float mu = s / n;
    const float rs = rsqrtf(q / n - mu * mu + 1e-5f);
    const float g  = gamma[o], be = beta[o];

    const f16* src = yh + ((size_t)b * COUT + o) * NL;
    float*     dst = y  + ((size_t)b * COUT + o) * NL;
    #pragma unroll
    for (int it = 0; it < 4; ++it) {
        const int base = it * 2048 + tid * 8;
        f16x8 v = *(const f16x8*)(src + base);
        float4 o1, o2;
        o1.x = fmaxf(fmaf(g, ((float)v[0] - mu) * rs, be), 0.0f);
        o1.y = fmaxf(fmaf(g, ((float)v[1] - mu) * rs, be), 0.0f);
        o1.z = fmaxf(fmaf(g, ((float)v[2] - mu) * rs, be), 0.0f);
        o1.w = fmaxf(fmaf(g, ((float)v[3] - mu) * rs, be), 0.0f);
        o2.x = fmaxf(fmaf(g, ((float)v[4] - mu) * rs, be), 0.0f);
        o2.y = fmaxf(fmaf(g, ((float)v[5] - mu) * rs, be), 0.0f);
        o2.z = fmaxf(fmaf(g, ((float)v[6] - mu) * rs, be), 0.0f);
        o2.w = fmaxf(fmaf(g, ((float)v[7] - mu) * rs, be), 0.0f);
        *(float4*)(dst + base)     = o1;
        *(float4*)(dst + base + 4) = o2;
    }
}

// ---------------------------------------------------------------------------
extern "C" void kernel_launch(void* const* d_in, const int* in_sizes, int n_in,
                              void* d_out, int out_size, void* d_ws, size_t ws_size,
                              hipStream_t stream)
{
    const float* xyz_low   = (const float*)d_in[0];
    const float* xyz_high  = (const float*)d_in[1];
    const float* feat_low  = (const float*)d_in[2];
    const float* feat_high = (const float*)d_in[3];
    const float* Wm        = (const float*)d_in[4];
    const float* bias      = (const float*)d_in[5];
    const float* gamma     = (const float*)d_in[6];
    const float* beta      = (const float*)d_in[7];
    float* y = (float*)d_out;

    float* ps   = (float*)d_ws;                        // 256*512 f32
    float* psq  = ps + (size_t)COUT * 512;             // 256*512 f32
    float* cdG  = psq + (size_t)COUT * 512;            // 2048*384 f32
    int*   ciG  = (int*)(cdG + (size_t)2048 * 384);    // 2048*384 i32
    f16*   Wh   = (f16*)(ciG + (size_t)2048 * 384);    // 256*384 f16
    f16*   fhT  = Wh + (size_t)COUT * CIN;             // 4*2048*256 f16 (4.2MB)
    f16*   flT  = fhT + (size_t)B_ * NH * CH;          // 4*8192*128 f16 (8.4MB)
    f16*   yh   = flT + (size_t)B_ * NL * CL;          // 4*256*8192 f16 (16.8MB)
    f16*   ficat = (f16*)d_out;                        // scratch: dead by K4

    knn_prep_kernel<<<3968, 256, 0, stream>>>(
        xyz_low, xyz_high, feat_high, feat_low, Wm, fhT, flT, Wh, cdG, ciG);
    interp_kernel<<<2048, 256, 0, stream>>>(fhT, cdG, ciG, ficat);
    gemm_kernel<<<512, 512, 0, stream>>>(
        flT, ficat, Wh, bias, yh, ps, psq);
    stats_apply_kernel<<<dim3(COUT, B_), 256, 0, stream>>>(
        ps, psq, yh, gamma, beta, y);
}

// Round 14
// 78.430 us; speedup vs baseline: 1.1321x; 1.0879x over previous
//
#include <hip/hip_runtime.h>

constexpr int B_   = 4;
constexpr int NL   = 8192;
constexpr int NH   = 2048;
constexpr int CH   = 256;
constexpr int CL   = 128;
constexpr int CIN  = 384;
constexpr int COUT = 256;

typedef _Float16 f16;
typedef _Float16 f16x8 __attribute__((ext_vector_type(8)));
typedef float    f32x4 __attribute__((ext_vector_type(4)));

// Fast branchless top-3 insert: 3 cmp + 5 cndmask (indices) + min/med3/med3
// (values) = 11 flat ops, dependency depth 2. Bit-equivalent to the
// sequential strict-< insert incl. earliest-index-wins on exact ties.
#define INS3F(d, h, B0, B1, B2, I0, I1, I2) do {                             \
    bool c0_ = (d) < (B0), c1_ = (d) < (B1), c2_ = (d) < (B2);               \
    int ni1_ = c0_ ? (I0) : (c1_ ? (h) : (I1));                              \
    int ni2_ = c1_ ? (I1) : (c2_ ? (h) : (I2));                              \
    I0 = c0_ ? (h) : (I0); I1 = ni1_; I2 = ni2_;                             \
    float nb1_ = __builtin_amdgcn_fmed3f(B0, B1, (d));                       \
    float nb2_ = __builtin_amdgcn_fmed3f(B1, B2, (d));                       \
    B0 = fminf(B0, (d)); B1 = nb1_; B2 = nb2_;                               \
} while (0)

// ---------------------------------------------------------------------------
// K1: role-fused.
//   [0,2048):    3-NN eighth-range blocks: block=(tile<<3)|oct. 128 low pts
//                (2 per lane) vs h in [oct*256, oct*256+256). Wave w scans a
//                64-h slice; pts[h] wave-uniform -> LDS broadcast. 12-way
//                slice-order merge -> per-octant top-3 (d2,idx) to cdG/ciG.
//   [2048,2560): fhT transpose (B,CH,NH) f32 -> (B,NH,CH) f16.
//   [2560,2944): W f32 -> f16.
// ---------------------------------------------------------------------------
__global__ __launch_bounds__(256) void knn_prep_kernel(
    const float* __restrict__ xyz_low, const float* __restrict__ xyz_high,
    const float* __restrict__ feat_high, const float* __restrict__ Wm,
    f16* __restrict__ fhT, f16* __restrict__ Wh,
    float* __restrict__ cdG, int* __restrict__ ciG)
{
    __shared__ __align__(16) char smraw[14080];
    const int bid = blockIdx.x, tid = threadIdx.x;

    if (bid < 2048) {
        float4*         pts = (float4*)smraw;                  // [0, 4096)
        float*          md  = (float*)(smraw + 4096);          // 128*13 f32
        unsigned short* mi  = (unsigned short*)(smraw + 10752);// 128*13 u16
        const int tile = bid >> 3, oct = bid & 7;
        const int b = tile >> 6, l0 = (tile & 63) * 128;
        const int w = tid >> 6, p = tid & 63;
        const int hbase = oct * 256;

        const float* xh = xyz_high + ((size_t)b * NH + hbase) * 3;
        {
            const int h = tid;  // 256 pts, 256 threads
            float x = xh[h * 3], yy = xh[h * 3 + 1], z = xh[h * 3 + 2];
            pts[h] = make_float4(x, yy, z, x * x + yy * yy + z * z);
        }
        __syncthreads();

        const float* xlA = xyz_low + ((size_t)b * NL + l0 + p) * 3;
        const float* xlB = xyz_low + ((size_t)b * NL + l0 + 64 + p) * 3;
        const float lxA = xlA[0], lyA = xlA[1], lzA = xlA[2];
        const float lxB = xlB[0], lyB = xlB[1], lzB = xlB[2];
        const float slA = lxA * lxA + lyA * lyA + lzA * lzA;
        const float slB = lxB * lxB + lyB * lyB + lzB * lzB;

        float a0 = 1e30f, a1 = 1e30f, a2 = 1e30f;
        float c0 = 1e30f, c1 = 1e30f, c2 = 1e30f;
        int ia0 = 0, ia1 = 0, ia2 = 0, ic0 = 0, ic1 = 0, ic2 = 0;
        const int h0 = w * 64;
        #pragma unroll 4
        for (int h = h0; h < h0 + 64; ++h) {
            float4 pt = pts[h];
            float dA = fmaf(-2.0f, fmaf(lxA, pt.x, fmaf(lyA, pt.y, lzA * pt.z)),
                            slA + pt.w);
            float dB = fmaf(-2.0f, fmaf(lxB, pt.x, fmaf(lyB, pt.y, lzB * pt.z)),
                            slB + pt.w);
            INS3F(dA, h, a0, a1, a2, ia0, ia1, ia2);
            INS3F(dB, h, c0, c1, c2, ic0, ic1, ic2);
        }
        const int cbA = p * 13 + w * 3;
        const int cbB = (p + 64) * 13 + w * 3;
        md[cbA] = a0;     mi[cbA] = (unsigned short)(hbase + ia0);
        md[cbA + 1] = a1; mi[cbA + 1] = (unsigned short)(hbase + ia1);
        md[cbA + 2] = a2; mi[cbA + 2] = (unsigned short)(hbase + ia2);
        md[cbB] = c0;     mi[cbB] = (unsigned short)(hbase + ic0);
        md[cbB + 1] = c1; mi[cbB + 1] = (unsigned short)(hbase + ic1);
        md[cbB + 2] = c2; mi[cbB + 2] = (unsigned short)(hbase + ic2);
        __syncthreads();

        if (tid < 128) {  // merge 12 in slice order (h ascending, tie-stable)
            float e0 = 1e30f, e1 = 1e30f, e2 = 1e30f;
            int j0 = 0, j1 = 0, j2 = 0;
            #pragma unroll
            for (int q = 0; q < 12; ++q) {
                float d = md[tid * 13 + q];
                int  ii = mi[tid * 13 + q];
                INS3F(d, ii, e0, e1, e2, j0, j1, j2);
            }
            const size_t dst = (size_t)bid * 384 + tid;
            cdG[dst]       = e0; ciG[dst]       = j0;
            cdG[dst + 128] = e1; ciG[dst + 128] = j1;
            cdG[dst + 256] = e2; ciG[dst + 256] = j2;
        }
    } else if (bid < 2560) {
        float (*tt)[33] = (float(*)[33])smraw;
        const int tx = tid & 31, ty = tid >> 5;
        #pragma unroll
        for (int k = 0; k < 4; ++k) {
            const int u  = (bid - 2048) * 4 + k;       // 2048 tiles
            const int ub = u >> 9, ut = u & 511;
            const int h0 = (ut & 63) * 32, c0 = (ut >> 6) * 32;
            #pragma unroll
            for (int pp = 0; pp < 4; ++pp)
                tt[ty + pp * 8][tx] =
                    feat_high[((size_t)ub * CH + c0 + ty + pp * 8) * NH + h0 + tx];
            __syncthreads();
            #pragma unroll
            for (int pp = 0; pp < 4; ++pp)
                fhT[((size_t)ub * NH + h0 + ty + pp * 8) * CH + c0 + tx] =
                    (f16)tt[tx][ty + pp * 8];
            __syncthreads();
        }
    } else {
        const int i = (bid - 2560) * 256 + tid;        // 384 blocks
        Wh[i] = (f16)Wm[i];
    }
}

// ---------------------------------------------------------------------------
// K2: fused merge + interp + GEMM. 512 blocks x 512 thr (16 waves/CU).
// Tile 256(o) x 64(l). Prologue: cross-octant merge (h order, strict < ->
// exact tie semantics) -> weights; interp gather straight into As[64][392];
// feat_low staged direct from f32 (lane-coalesced). Barrier-free 12-kt
// K-loop (W A-frags from L2-hot global; B-frags from LDS As); bias into
// acc; per-block BN partials; yh f16 via LDS-coalesced 128B/row stores.
// ---------------------------------------------------------------------------
__global__ __launch_bounds__(512) void gemm_kernel(
    const float* __restrict__ feat_low, const f16* __restrict__ fhT,
    const f16* __restrict__ Wh, const float* __restrict__ bias,
    const float* __restrict__ cdG, const int* __restrict__ ciG,
    f16* __restrict__ yh, float* __restrict__ ps, float* __restrict__ psq)
{
    // As [0,50176) = [64][392] f16 ; idxL [50176,50944) ; wL [50944,51712)
    __shared__ __align__(16) char smraw[51712];
    f16*   As   = (f16*)smraw;
    int*   idxL = (int*)(smraw + 50176);   // [3][64]
    float* wL   = (float*)(smraw + 50944); // [3][64]

    const int bid = blockIdx.x, tid = threadIdx.x;
    const int b = bid >> 7, l0 = (bid & 127) * 64;
    const int lane = tid & 63, w = tid >> 6;

    if (tid < 64) {   // cross-octant merge + weights for the 64 points
        float e0 = 1e30f, e1 = 1e30f, e2 = 1e30f;
        int j0 = 0, j1 = 0, j2 = 0;
        const int t128 = b * 64 + ((bid & 127) >> 1);  // 128-pt tile
        const int poff = (bid & 1) * 64 + tid;
        #pragma unroll
        for (int oct = 0; oct < 8; ++oct) {
            const size_t src = (size_t)(t128 * 8 + oct) * 384 + poff;
            #pragma unroll
            for (int q = 0; q < 3; ++q) {
                float d = cdG[src + q * 128];
                int  ii = ciG[src + q * 128];
                INS3F(d, ii, e0, e1, e2, j0, j1, j2);
            }
        }
        float d0 = sqrtf(fmaxf(e0, 0.0f));
        float d1 = sqrtf(fmaxf(e1, 0.0f));
        float d2f = sqrtf(fmaxf(e2, 0.0f));
        float iw0 = 1.0f / fmaxf(d0, 1e-8f);
        float iw1 = 1.0f / fmaxf(d1, 1e-8f);
        float iw2 = 1.0f / fmaxf(d2f, 1e-8f);
        float sum = iw0 + iw1 + iw2;
        idxL[tid] = j0; idxL[64 + tid] = j1; idxL[128 + tid] = j2;
        wL[tid] = iw0 / sum; wL[64 + tid] = iw1 / sum; wL[128 + tid] = iw2 / sum;
    }
    __syncthreads();

    {   // interp gather: p = tid>>3 (point), q = tid&7 (32 channels each).
        // 8 adjacent lanes read one 512B fhT row chunk-contiguously.
        const int p = tid >> 3, q = tid & 7;
        const int j0 = idxL[p], j1 = idxL[64 + p], j2 = idxL[128 + p];
        const float u0 = wL[p], u1 = wL[64 + p], u2 = wL[128 + p];
        const f16* r0 = fhT + ((size_t)b * NH + j0) * CH + q * 32;
        const f16* r1 = fhT + ((size_t)b * NH + j1) * CH + q * 32;
        const f16* r2 = fhT + ((size_t)b * NH + j2) * CH + q * 32;
        #pragma unroll
        for (int j = 0; j < 4; ++j) {
            f16x8 v0 = *(const f16x8*)(r0 + j * 8);
            f16x8 v1 = *(const f16x8*)(r1 + j * 8);
            f16x8 v2 = *(const f16x8*)(r2 + j * 8);
            f16x8 o;
            #pragma unroll
            for (int e = 0; e < 8; ++e)
                o[e] = (f16)(u0 * (float)v0[e] + u1 * (float)v1[e]
                             + u2 * (float)v2[e]);
            *(f16x8*)&As[p * 392 + q * 32 + j * 8] = o;
        }
        // feat_low direct: l = tid&63 (coalesced), cq = tid>>6 (16 ch each)
        const int l = tid & 63, cq = tid >> 6;
        const float* flb = feat_low + ((size_t)b * CL + cq * 16) * NL + l0 + l;
        f16 tmp[16];
        #pragma unroll
        for (int i = 0; i < 16; ++i)
            tmp[i] = (f16)flb[(size_t)i * NL];
        *(f16x8*)&As[l * 392 + 256 + cq * 16]     = *(const f16x8*)&tmp[0];
        *(f16x8*)&As[l * 392 + 256 + cq * 16 + 8] = *(const f16x8*)&tmp[8];
    }
    __syncthreads();

    f32x4 acc[2][4] = {};
    const int kb = (lane >> 4) * 8;
    const int r  = lane & 15;
    #pragma unroll
    for (int kt = 0; kt < 12; ++kt) {
        const int k0 = kt * 32;
        f16x8 a[2], bb[4];
        #pragma unroll
        for (int mi = 0; mi < 2; ++mi)
            a[mi] = *(const f16x8*)&Wh[(size_t)(w * 32 + mi * 16 + r) * CIN
                                       + k0 + kb];
        #pragma unroll
        for (int ni = 0; ni < 4; ++ni)
            bb[ni] = *(const f16x8*)&As[(ni * 16 + r) * 392 + k0 + kb];
        #pragma unroll
        for (int mi = 0; mi < 2; ++mi)
            #pragma unroll
            for (int ni = 0; ni < 4; ++ni)
                acc[mi][ni] = __builtin_amdgcn_mfma_f32_16x16x32_f16(
                    a[mi], bb[ni], acc[mi][ni], 0, 0, 0);
    }

    // bias into acc + per-block BN partials (no LDS touched)
    const int r4 = (lane >> 4) * 4, cl = lane & 15;
    #pragma unroll
    for (int mi = 0; mi < 2; ++mi) {
        #pragma unroll
        for (int j = 0; j < 4; ++j) {
            const int o = w * 32 + mi * 16 + r4 + j;
            const float bi = bias[o];
            float s = 0.0f, sq = 0.0f;
            #pragma unroll
            for (int ni = 0; ni < 4; ++ni) {
                acc[mi][ni][j] += bi;
                float v = acc[mi][ni][j];
                s += v; sq += v * v;
            }
            #pragma unroll
            for (int m = 1; m < 16; m <<= 1) {
                s  += __shfl_xor(s, m);
                sq += __shfl_xor(sq, m);
            }
            if (cl == 0) {
                ps [o * 512 + bid] = s;
                psq[o * 512 + bid] = sq;
            }
        }
    }
    __syncthreads();   // all As reads done -> safe to alias with Ys

    f16* Ys = (f16*)smraw;             // [256][72] f16 = 36864 B
    #pragma unroll
    for (int mi = 0; mi < 2; ++mi)
        #pragma unroll
        for (int j = 0; j < 4; ++j) {
            const int o = w * 32 + mi * 16 + r4 + j;
            #pragma unroll
            for (int ni = 0; ni < 4; ++ni)
                Ys[o * 72 + cl + ni * 16] = (f16)acc[mi][ni][j];
        }
    __syncthreads();
    {   // store: 2 threads per o-row -> 128B contiguous per row
        const int o = tid >> 1, half = tid & 1;
        f16* dst = yh + ((size_t)b * COUT + o) * NL + l0 + half * 32;
        #pragma unroll
        for (int j = 0; j < 4; ++j)
            *(f16x8*)(dst + j * 8) = *(const f16x8*)&Ys[o * 72 + half * 32 + j * 8];
    }
}

// ---------------------------------------------------------------------------
// K3: fused BN stats + apply + ReLU. Grid (COUT, B_): each block reduces its
// channel's 512 partials (deterministic, redundant across b-blocks) then
// applies to its (b,o) row of 8192.
// ---------------------------------------------------------------------------
__global__ __launch_bounds__(256) void stats_apply_kernel(
    const float* __restrict__ ps, const float* __restrict__ psq,
    const f16* __restrict__ yh,
    const float* __restrict__ gamma, const float* __restrict__ beta,
    float* __restrict__ y)
{
    const int o = blockIdx.x, b = blockIdx.y, tid = threadIdx.x;
    const int w = tid >> 6, lane = tid & 63;

    float s = ps[o * 512 + tid] + ps[o * 512 + 256 + tid];
    float q = psq[o * 512 + tid] + psq[o * 512 + 256 + tid];
    #pragma unroll
    for (int m = 32; m > 0; m >>= 1) {
        s += __shfl_down(s, m);
        q += __shfl_down(q, m);
    }
    __shared__ float red[8];
    if (lane == 0) { red[w] = s; red[4 + w] = q; }
    __syncthreads();
    s = red[0] + red[1] + red[2] + red[3];
    q = red[4] + red[5] + red[6] + red[7];
    const float n  = (float)(B_ * NL);
    const float mu = s / n;
    const float rs = rsqrtf(q / n - mu * mu + 1e-5f);
    const float g  = gamma[o], be = beta[o];

    const f16* src = yh + ((size_t)b * COUT + o) * NL;
    float*     dst = y  + ((size_t)b * COUT + o) * NL;
    #pragma unroll
    for (int it = 0; it < 4; ++it) {
        const int base = it * 2048 + tid * 8;
        f16x8 v = *(const f16x8*)(src + base);
        float4 o1, o2;
        o1.x = fmaxf(fmaf(g, ((float)v[0] - mu) * rs, be), 0.0f);
        o1.y = fmaxf(fmaf(g, ((float)v[1] - mu) * rs, be), 0.0f);
        o1.z = fmaxf(fmaf(g, ((float)v[2] - mu) * rs, be), 0.0f);
        o1.w = fmaxf(fmaf(g, ((float)v[3] - mu) * rs, be), 0.0f);
        o2.x = fmaxf(fmaf(g, ((float)v[4] - mu) * rs, be), 0.0f);
        o2.y = fmaxf(fmaf(g, ((float)v[5] - mu) * rs, be), 0.0f);
        o2.z = fmaxf(fmaf(g, ((float)v[6] - mu) * rs, be), 0.0f);
        o2.w = fmaxf(fmaf(g, ((float)v[7] - mu) * rs, be), 0.0f);
        *(float4*)(dst + base)     = o1;
        *(float4*)(dst + base + 4) = o2;
    }
}

// ---------------------------------------------------------------------------
extern "C" void kernel_launch(void* const* d_in, const int* in_sizes, int n_in,
                              void* d_out, int out_size, void* d_ws, size_t ws_size,
                              hipStream_t stream)
{
    const float* xyz_low   = (const float*)d_in[0];
    const float* xyz_high  = (const float*)d_in[1];
    const float* feat_low  = (const float*)d_in[2];
    const float* feat_high = (const float*)d_in[3];
    const float* Wm        = (const float*)d_in[4];
    const float* bias      = (const float*)d_in[5];
    const float* gamma     = (const float*)d_in[6];
    const float* beta      = (const float*)d_in[7];
    float* y = (float*)d_out;

    float* ps   = (float*)d_ws;                        // 256*512 f32
    float* psq  = ps + (size_t)COUT * 512;             // 256*512 f32
    float* cdG  = psq + (size_t)COUT * 512;            // 2048*384 f32
    int*   ciG  = (int*)(cdG + (size_t)2048 * 384);    // 2048*384 i32
    f16*   Wh   = (f16*)(ciG + (size_t)2048 * 384);    // 256*384 f16
    f16*   fhT  = Wh + (size_t)COUT * CIN;             // 4*2048*256 f16 (4.2MB)
    f16*   yh   = fhT + (size_t)B_ * NH * CH;          // 4*256*8192 f16 (16.8MB)

    knn_prep_kernel<<<2944, 256, 0, stream>>>(
        xyz_low, xyz_high, feat_high, Wm, fhT, Wh, cdG, ciG);
    gemm_kernel<<<512, 512, 0, stream>>>(
        feat_low, fhT, Wh, bias, cdG, ciG, yh, ps, psq);
    stats_apply_kernel<<<dim3(COUT, B_), 256, 0, stream>>>(
        ps, psq, yh, gamma, beta, y);
}

// Round 15
// 75.818 us; speedup vs baseline: 1.1711x; 1.0345x over previous
//
#include <hip/hip_runtime.h>

constexpr int B_   = 4;
constexpr int NL   = 8192;
constexpr int NH   = 2048;
constexpr int CH   = 256;
constexpr int CL   = 128;
constexpr int CIN  = 384;
constexpr int COUT = 256;

typedef _Float16 f16;
typedef _Float16 f16x8 __attribute__((ext_vector_type(8)));
typedef float    f32x4 __attribute__((ext_vector_type(4)));

// Fast branchless top-3 insert: 3 cmp + 5 cndmask (indices) + min/med3/med3
// (values) = 11 flat ops, dependency depth 2. Bit-equivalent to the
// sequential strict-< insert incl. earliest-index-wins on exact ties.
#define INS3F(d, h, B0, B1, B2, I0, I1, I2) do {                             \
    bool c0_ = (d) < (B0), c1_ = (d) < (B1), c2_ = (d) < (B2);               \
    int ni1_ = c0_ ? (I0) : (c1_ ? (h) : (I1));                              \
    int ni2_ = c1_ ? (I1) : (c2_ ? (h) : (I2));                              \
    I0 = c0_ ? (h) : (I0); I1 = ni1_; I2 = ni2_;                             \
    float nb1_ = __builtin_amdgcn_fmed3f(B0, B1, (d));                       \
    float nb2_ = __builtin_amdgcn_fmed3f(B1, B2, (d));                       \
    B0 = fminf(B0, (d)); B1 = nb1_; B2 = nb2_;                               \
} while (0)

// ---------------------------------------------------------------------------
// K1: prep only.
//   [0,512):   fhT transpose (B,CH,NH) f32 -> (B,NH,CH) f16 (4 tiles each).
//   [512,896): W f32 -> f16.
// ---------------------------------------------------------------------------
__global__ __launch_bounds__(256) void prep_kernel(
    const float* __restrict__ feat_high, const float* __restrict__ Wm,
    f16* __restrict__ fhT, f16* __restrict__ Wh)
{
    __shared__ float tt[32][33];
    const int bid = blockIdx.x, tid = threadIdx.x;

    if (bid < 512) {
        const int tx = tid & 31, ty = tid >> 5;
        #pragma unroll
        for (int k = 0; k < 4; ++k) {
            const int u  = bid * 4 + k;            // 2048 tiles total
            const int ub = u >> 9, ut = u & 511;
            const int h0 = (ut & 63) * 32, c0 = (ut >> 6) * 32;
            #pragma unroll
            for (int pp = 0; pp < 4; ++pp)
                tt[ty + pp * 8][tx] =
                    feat_high[((size_t)ub * CH + c0 + ty + pp * 8) * NH + h0 + tx];
            __syncthreads();
            #pragma unroll
            for (int pp = 0; pp < 4; ++pp)
                fhT[((size_t)ub * NH + h0 + ty + pp * 8) * CH + c0 + tx] =
                    (f16)tt[tx][ty + pp * 8];
            __syncthreads();
        }
    } else {
        const int i = (bid - 512) * 256 + tid;     // 384 blocks
        Wh[i] = (f16)Wm[i];
    }
}

// ---------------------------------------------------------------------------
// K2: fused kNN + interp + GEMM. 512 blocks x 512 thr, 51.7 KB LDS
// (3 blocks/CU = 24 waves/CU).
// Phase A (knn): stage all 2048 high pts (aliases dead As region); wave w
//   scans h in [w*256,+128) and [+128,+256) — 2 independent chains/lane for
//   the block's 64 points (lane = point); local chain merge (all B-h > A-h
//   -> slot-order insert exact); 24-way w-ascending merge -> weights.
//   Bit-identical d2 + strict-< insert == reference top_k tie semantics.
// Phase B: interp gather -> As[64][392]; feat_low staged direct (coalesced).
// Phase C: barrier-free 12-kt MFMA K-loop (W from L2-hot global); bias;
//   per-block BN partials; yh f16 via LDS-staged 128B/row stores.
// ---------------------------------------------------------------------------
__global__ __launch_bounds__(512) void gemm_kernel(
    const float* __restrict__ xyz_low, const float* __restrict__ xyz_high,
    const float* __restrict__ feat_low, const f16* __restrict__ fhT,
    const f16* __restrict__ Wh, const float* __restrict__ bias,
    f16* __restrict__ yh, float* __restrict__ ps, float* __restrict__ psq)
{
    // As   [0,50176)      [64][392] f16 (gemm tile; Ys epilogue alias)
    // pts  [0,32768)      2048 float4  (dead before As written)
    // md   [32768,39168)  64*25 f32    (dead before As written)
    // mi   [39168,42368)  64*25 u16    (dead before As written)
    // idxL [50176,50944)  wL [50944,51712)  (live through gather)
    __shared__ __align__(16) char smraw[51712];
    f16*            As   = (f16*)smraw;
    float4*         pts  = (float4*)smraw;
    float*          md   = (float*)(smraw + 32768);
    unsigned short* mi   = (unsigned short*)(smraw + 39168);
    int*            idxL = (int*)(smraw + 50176);
    float*          wL   = (float*)(smraw + 50944);

    const int bid = blockIdx.x, tid = threadIdx.x;
    const int b = bid >> 7, l0 = (bid & 127) * 64;
    const int lane = tid & 63, w = tid >> 6;

    // ---- phase A: stage pts + 2-chain scan + merges ----
    {
        const float* xh = xyz_high + (size_t)b * NH * 3;
        #pragma unroll
        for (int k = 0; k < 4; ++k) {
            const int h = k * 512 + tid;
            float x = xh[h * 3], yy = xh[h * 3 + 1], z = xh[h * 3 + 2];
            pts[h] = make_float4(x, yy, z, x * x + yy * yy + z * z);
        }
    }
    __syncthreads();
    {
        const float* xl = xyz_low + ((size_t)b * NL + l0 + lane) * 3;
        const float lx = xl[0], ly = xl[1], lz = xl[2];
        const float sl = lx * lx + ly * ly + lz * lz;

        float a0 = 1e30f, a1 = 1e30f, a2 = 1e30f;
        float c0 = 1e30f, c1 = 1e30f, c2 = 1e30f;
        int ia0 = 0, ia1 = 0, ia2 = 0, ic0 = 0, ic1 = 0, ic2 = 0;
        const int hA = w * 256, hB = hA + 128;
        #pragma unroll 4
        for (int i = 0; i < 128; ++i) {
            float4 pA = pts[hA + i];
            float4 pB = pts[hB + i];
            float dA = fmaf(-2.0f, fmaf(lx, pA.x, fmaf(ly, pA.y, lz * pA.z)),
                            sl + pA.w);
            float dB = fmaf(-2.0f, fmaf(lx, pB.x, fmaf(ly, pB.y, lz * pB.z)),
                            sl + pB.w);
            INS3F(dA, hA + i, a0, a1, a2, ia0, ia1, ia2);
            INS3F(dB, hB + i, c0, c1, c2, ic0, ic1, ic2);
        }
        // local merge: chain-B candidates (all h > chain-A's) in slot order
        INS3F(c0, ic0, a0, a1, a2, ia0, ia1, ia2);
        INS3F(c1, ic1, a0, a1, a2, ia0, ia1, ia2);
        INS3F(c2, ic2, a0, a1, a2, ia0, ia1, ia2);
        const int cb = lane * 25 + w * 3;
        md[cb] = a0;     mi[cb] = (unsigned short)ia0;
        md[cb + 1] = a1; mi[cb + 1] = (unsigned short)ia1;
        md[cb + 2] = a2; mi[cb + 2] = (unsigned short)ia2;
    }
    __syncthreads();

    if (tid < 64) {   // 24-way merge in w-ascending (= h-ascending) order
        float e0 = 1e30f, e1 = 1e30f, e2 = 1e30f;
        int j0 = 0, j1 = 0, j2 = 0;
        #pragma unroll
        for (int q = 0; q < 24; ++q) {
            float d = md[tid * 25 + q];
            int  ii = mi[tid * 25 + q];
            INS3F(d, ii, e0, e1, e2, j0, j1, j2);
        }
        float d0 = sqrtf(fmaxf(e0, 0.0f));
        float d1 = sqrtf(fmaxf(e1, 0.0f));
        float d2f = sqrtf(fmaxf(e2, 0.0f));
        float iw0 = 1.0f / fmaxf(d0, 1e-8f);
        float iw1 = 1.0f / fmaxf(d1, 1e-8f);
        float iw2 = 1.0f / fmaxf(d2f, 1e-8f);
        float sum = iw0 + iw1 + iw2;
        idxL[tid] = j0; idxL[64 + tid] = j1; idxL[128 + tid] = j2;
        wL[tid] = iw0 / sum; wL[64 + tid] = iw1 / sum; wL[128 + tid] = iw2 / sum;
    }
    __syncthreads();

    // ---- phase B: interp gather + feat_low staging (pts/md/mi now dead) --
    {
        const int p = tid >> 3, q = tid & 7;
        const int j0 = idxL[p], j1 = idxL[64 + p], j2 = idxL[128 + p];
        const float u0 = wL[p], u1 = wL[64 + p], u2 = wL[128 + p];
        const f16* r0 = fhT + ((size_t)b * NH + j0) * CH + q * 32;
        const f16* r1 = fhT + ((size_t)b * NH + j1) * CH + q * 32;
        const f16* r2 = fhT + ((size_t)b * NH + j2) * CH + q * 32;
        #pragma unroll
        for (int j = 0; j < 4; ++j) {
            f16x8 v0 = *(const f16x8*)(r0 + j * 8);
            f16x8 v1 = *(const f16x8*)(r1 + j * 8);
            f16x8 v2 = *(const f16x8*)(r2 + j * 8);
            f16x8 o;
            #pragma unroll
            for (int e = 0; e < 8; ++e)
                o[e] = (f16)(u0 * (float)v0[e] + u1 * (float)v1[e]
                             + u2 * (float)v2[e]);
            *(f16x8*)&As[p * 392 + q * 32 + j * 8] = o;
        }
        const int l = tid & 63, cq = tid >> 6;
        const float* flb = feat_low + ((size_t)b * CL + cq * 16) * NL + l0 + l;
        f16 tmp[16];
        #pragma unroll
        for (int i = 0; i < 16; ++i)
            tmp[i] = (f16)flb[(size_t)i * NL];
        *(f16x8*)&As[l * 392 + 256 + cq * 16]     = *(const f16x8*)&tmp[0];
        *(f16x8*)&As[l * 392 + 256 + cq * 16 + 8] = *(const f16x8*)&tmp[8];
    }
    __syncthreads();

    // ---- phase C: MFMA K-loop + epilogue ----
    f32x4 acc[2][4] = {};
    const int kb = (lane >> 4) * 8;
    const int r  = lane & 15;
    #pragma unroll
    for (int kt = 0; kt < 12; ++kt) {
        const int k0 = kt * 32;
        f16x8 a[2], bb[4];
        #pragma unroll
        for (int mi2 = 0; mi2 < 2; ++mi2)
            a[mi2] = *(const f16x8*)&Wh[(size_t)(w * 32 + mi2 * 16 + r) * CIN
                                        + k0 + kb];
        #pragma unroll
        for (int ni = 0; ni < 4; ++ni)
            bb[ni] = *(const f16x8*)&As[(ni * 16 + r) * 392 + k0 + kb];
        #pragma unroll
        for (int mi2 = 0; mi2 < 2; ++mi2)
            #pragma unroll
            for (int ni = 0; ni < 4; ++ni)
                acc[mi2][ni] = __builtin_amdgcn_mfma_f32_16x16x32_f16(
                    a[mi2], bb[ni], acc[mi2][ni], 0, 0, 0);
    }

    const int r4 = (lane >> 4) * 4, cl = lane & 15;
    #pragma unroll
    for (int mi2 = 0; mi2 < 2; ++mi2) {
        #pragma unroll
        for (int j = 0; j < 4; ++j) {
            const int o = w * 32 + mi2 * 16 + r4 + j;
            const float bi = bias[o];
            float s = 0.0f, sq = 0.0f;
            #pragma unroll
            for (int ni = 0; ni < 4; ++ni) {
                acc[mi2][ni][j] += bi;
                float v = acc[mi2][ni][j];
                s += v; sq += v * v;
            }
            #pragma unroll
            for (int m = 1; m < 16; m <<= 1) {
                s  += __shfl_xor(s, m);
                sq += __shfl_xor(sq, m);
            }
            if (cl == 0) {
                ps [o * 512 + bid] = s;
                psq[o * 512 + bid] = sq;
            }
        }
    }
    __syncthreads();   // all As reads done -> safe to alias with Ys

    f16* Ys = (f16*)smraw;             // [256][72] f16 = 36864 B
    #pragma unroll
    for (int mi2 = 0; mi2 < 2; ++mi2)
        #pragma unroll
        for (int j = 0; j < 4; ++j) {
            const int o = w * 32 + mi2 * 16 + r4 + j;
            #pragma unroll
            for (int ni = 0; ni < 4; ++ni)
                Ys[o * 72 + cl + ni * 16] = (f16)acc[mi2][ni][j];
        }
    __syncthreads();
    {   // store: 2 threads per o-row -> 128B contiguous per row
        const int o = tid >> 1, half = tid & 1;
        f16* dst = yh + ((size_t)b * COUT + o) * NL + l0 + half * 32;
        #pragma unroll
        for (int j = 0; j < 4; ++j)
            *(f16x8*)(dst + j * 8) = *(const f16x8*)&Ys[o * 72 + half * 32 + j * 8];
    }
}

// ---------------------------------------------------------------------------
// K3: fused BN stats + apply + ReLU. Grid (COUT, B_): each block reduces its
// channel's 512 partials (deterministic, redundant across b-blocks) then
// applies to its (b,o) row of 8192.
// ---------------------------------------------------------------------------
__global__ __launch_bounds__(256) void stats_apply_kernel(
    const float* __restrict__ ps, const float* __restrict__ psq,
    const f16* __restrict__ yh,
    const float* __restrict__ gamma, const float* __restrict__ beta,
    float* __restrict__ y)
{
    const int o = blockIdx.x, b = blockIdx.y, tid = threadIdx.x;
    const int w = tid >> 6, lane = tid & 63;

    float s = ps[o * 512 + tid] + ps[o * 512 + 256 + tid];
    float q = psq[o * 512 + tid] + psq[o * 512 + 256 + tid];
    #pragma unroll
    for (int m = 32; m > 0; m >>= 1) {
        s += __shfl_down(s, m);
        q += __shfl_down(q, m);
    }
    __shared__ float red[8];
    if (lane == 0) { red[w] = s; red[4 + w] = q; }
    __syncthreads();
    s = red[0] + red[1] + red[2] + red[3];
    q = red[4] + red[5] + red[6] + red[7];
    const float n  = (float)(B_ * NL);
    const float mu = s / n;
    const float rs = rsqrtf(q / n - mu * mu + 1e-5f);
    const float g  = gamma[o], be = beta[o];

    const f16* src = yh + ((size_t)b * COUT + o) * NL;
    float*     dst = y  + ((size_t)b * COUT + o) * NL;
    #pragma unroll
    for (int it = 0; it < 4; ++it) {
        const int base = it * 2048 + tid * 8;
        f16x8 v = *(const f16x8*)(src + base);
        float4 o1, o2;
        o1.x = fmaxf(fmaf(g, ((float)v[0] - mu) * rs, be), 0.0f);
        o1.y = fmaxf(fmaf(g, ((float)v[1] - mu) * rs, be), 0.0f);
        o1.z = fmaxf(fmaf(g, ((float)v[2] - mu) * rs, be), 0.0f);
        o1.w = fmaxf(fmaf(g, ((float)v[3] - mu) * rs, be), 0.0f);
        o2.x = fmaxf(fmaf(g, ((float)v[4] - mu) * rs, be), 0.0f);
        o2.y = fmaxf(fmaf(g, ((float)v[5] - mu) * rs, be), 0.0f);
        o2.z = fmaxf(fmaf(g, ((float)v[6] - mu) * rs, be), 0.0f);
        o2.w = fmaxf(fmaf(g, ((float)v[7] - mu) * rs, be), 0.0f);
        *(float4*)(dst + base)     = o1;
        *(float4*)(dst + base + 4) = o2;
    }
}

// ---------------------------------------------------------------------------
extern "C" void kernel_launch(void* const* d_in, const int* in_sizes, int n_in,
                              void* d_out, int out_size, void* d_ws, size_t ws_size,
                              hipStream_t stream)
{
    const float* xyz_low   = (const float*)d_in[0];
    const float* xyz_high  = (const float*)d_in[1];
    const float* feat_low  = (const float*)d_in[2];
    const float* feat_high = (const float*)d_in[3];
    const float* Wm        = (const float*)d_in[4];
    const float* bias      = (const float*)d_in[5];
    const float* gamma     = (const float*)d_in[6];
    const float* beta      = (const float*)d_in[7];
    float* y = (float*)d_out;

    float* ps   = (float*)d_ws;                        // 256*512 f32
    float* psq  = ps + (size_t)COUT * 512;             // 256*512 f32
    f16*   Wh   = (f16*)(psq + (size_t)COUT * 512);    // 256*384 f16
    f16*   fhT  = Wh + (size_t)COUT * CIN;             // 4*2048*256 f16 (4.2MB)
    f16*   yh   = fhT + (size_t)B_ * NH * CH;          // 4*256*8192 f16 (16.8MB)

    prep_kernel<<<896, 256, 0, stream>>>(feat_high, Wm, fhT, Wh);
    gemm_kernel<<<512, 512, 0, stream>>>(
        xyz_low, xyz_high, feat_low, fhT, Wh, bias, yh, ps, psq);
    stats_apply_kernel<<<dim3(COUT, B_), 256, 0, stream>>>(
        ps, psq, yh, gamma, beta, y);
}